// Round 2
// baseline (69.003 us; speedup 1.0000x reference)
//
#include <hip/hip_runtime.h>

typedef float f4 __attribute__((ext_vector_type(4)));

#define TT 4096
#define CC 128
#define BB 32
#define NG 32             // t-groups for partial moments
#define C4 (CC / 4)       // 32 float4 per row
#define ROWS_G (TT / NG)  // 128 rows per moment block

// ---------------------------------------------------------------------------
// Kernel 1: partial moments m0 = sum x, m1 = sum u*x, m2 = sum u^2*x
// over a 128-row t-slab, per (b, c). 256 threads = 8 row-groups x 32 c-quads.
// ---------------------------------------------------------------------------
__global__ __launch_bounds__(256) void k_moments(const f4* __restrict__ x4,
                                                 f4* __restrict__ partial,
                                                 float scale) {
    const int blk = blockIdx.x;
    const int b = blk >> 5;    // / NG
    const int g = blk & 31;    // % NG
    const int tid = threadIdx.x;
    const int r = tid >> 5;    // 0..7  row sub-group
    const int q = tid & 31;    // 0..31 c-quad
    const f4* xb = x4 + (size_t)b * TT * C4;
    const int t0 = g * ROWS_G;

    f4 m0 = (f4)0.0f, m1 = (f4)0.0f, m2 = (f4)0.0f;
#pragma unroll
    for (int k = 0; k < ROWS_G / 8; ++k) {   // 16 iterations
        const int t = t0 + r + (k << 3);
        const float u = fmaf((float)t, scale, -0.5f);
        const f4 v = xb[(size_t)t * C4 + q];
        m0 += v;
        m1 += u * v;
        m2 += (u * u) * v;
    }

    __shared__ f4 red[3][8][32];
    red[0][r][q] = m0;
    red[1][r][q] = m1;
    red[2][r][q] = m2;
    __syncthreads();

    if (tid < 32) {
#pragma unroll
        for (int j = 0; j < 3; ++j) {
            f4 s = red[j][0][tid];
#pragma unroll
            for (int rr = 1; rr < 8; ++rr) s += red[j][rr][tid];
            partial[(size_t)blk * (3 * C4) + j * C4 + tid] = s;
        }
    }
}

// ---------------------------------------------------------------------------
// Kernel 1b: reduce NG partials and normalize with the orthogonal-basis
// scalars. coef layout: [B][3][C4] float4.
// ---------------------------------------------------------------------------
__global__ __launch_bounds__(64) void k_coef(const f4* __restrict__ partial,
                                             f4* __restrict__ coef,
                                             float invS0, float invS2,
                                             float invD, float c20) {
    const int b = blockIdx.x;
    const int q = threadIdx.x;
    if (q >= C4) return;
    f4 s0 = (f4)0.0f, s1 = (f4)0.0f, s2 = (f4)0.0f;
    const f4* p = partial + (size_t)b * NG * (3 * C4);
    for (int g = 0; g < NG; ++g) {
        s0 += p[g * (3 * C4) + 0 * C4 + q];
        s1 += p[g * (3 * C4) + 1 * C4 + q];
        s2 += p[g * (3 * C4) + 2 * C4 + q];
    }
    coef[(size_t)b * (3 * C4) + 0 * C4 + q] = s0 * invS0;
    coef[(size_t)b * (3 * C4) + 1 * C4 + q] = s1 * invS2;
    coef[(size_t)b * (3 * C4) + 2 * C4 + q] = (s2 - c20 * s0) * invD;
}

// ---------------------------------------------------------------------------
// Kernel 2 (fused): low = a0 + u*a1 + (u^2-c20)*a2 ; res = x - low;
// and zero the two "high" output planes for the same index range.
// All stores nontemporal (streaming; keep x resident in L3 for the re-read).
// ---------------------------------------------------------------------------
__global__ __launch_bounds__(256) void k_emit_fused(const f4* __restrict__ x4,
                                                    const f4* __restrict__ coef,
                                                    f4* __restrict__ out,
                                                    float scale, float c20) {
    const size_t N4 = (size_t)BB * TT * C4;   // one output plane, in f4 units
    const int blk = blockIdx.x;
    const int b = blk >> 6;    // 64 tiles per batch
    const int tile = blk & 63;
    const int tid = threadIdx.x;
    const int r = tid >> 5;
    const int q = tid & 31;

    __shared__ f4 ca[3 * C4];
    if (tid < 3 * C4) ca[tid] = coef[(size_t)b * (3 * C4) + tid];
    __syncthreads();

    const f4 a0 = ca[0 * C4 + q];
    const f4 a1 = ca[1 * C4 + q];
    const f4 a2 = ca[2 * C4 + q];
    const f4 z = (f4)0.0f;

    const size_t base = (size_t)b * TT * C4;
    const int t0 = tile * 64;
#pragma unroll
    for (int k = 0; k < 8; ++k) {
        const int t = t0 + r + (k << 3);
        const float u = fmaf((float)t, scale, -0.5f);
        const float w = fmaf(u, u, -c20);
        const size_t idx = base + (size_t)t * C4 + q;
        const f4 xv = x4[idx];
        const f4 lo = a0 + u * a1 + w * a2;
        const f4 re = xv - lo;
        __builtin_nontemporal_store(lo, &out[idx]);
        __builtin_nontemporal_store(re, &out[N4 + idx]);
        __builtin_nontemporal_store(z, &out[2 * N4 + idx]);
        __builtin_nontemporal_store(z, &out[3 * N4 + idx]);
    }
}

// ---------------------------------------------------------------------------
extern "C" void kernel_launch(void* const* d_in, const int* in_sizes, int n_in,
                              void* d_out, int out_size, void* d_ws, size_t ws_size,
                              hipStream_t stream) {
    const float* x = (const float*)d_in[0];
    float* out = (float*)d_out;
    const size_t N = (size_t)BB * TT * CC;   // 16,777,216 per plane

    // Exact basis scalars in double on host (t symmetric => S1 = S3 = 0).
    double S0 = (double)TT, S2 = 0.0, S4 = 0.0;
    for (int i = 0; i < TT; ++i) {
        double u = (double)i / (double)(TT - 1) - 0.5;
        double u2 = u * u;
        S2 += u2;
        S4 += u2 * u2;
    }
    const double c20d = S2 / S0;               // mean of u^2
    const double Dd = S4 - S2 * S2 / S0;       // ||u^2 - c20||^2
    const float scale = (float)(1.0 / (double)(TT - 1));

    const size_t partial_elems = (size_t)BB * NG * 3 * C4;  // f4 units
    const size_t coef_elems    = (size_t)BB * 3 * C4;       // f4 units
    const size_t need_bytes    = (partial_elems + coef_elems) * sizeof(f4);

    if (ws_size >= need_bytes) {
        // Fast path: scratch in d_ws; zero planes fused into the emit kernel.
        f4* partial = (f4*)d_ws;
        f4* coef    = partial + partial_elems;
        k_moments<<<BB * NG, 256, 0, stream>>>((const f4*)x, partial, scale);
        k_coef<<<BB, 64, 0, stream>>>(partial, coef,
                                      (float)(1.0 / S0), (float)(1.0 / S2),
                                      (float)(1.0 / Dd), (float)c20d);
        k_emit_fused<<<BB * 64, 256, 0, stream>>>((const f4*)x, coef, (f4*)out,
                                                  scale, (float)c20d);
    } else {
        // Fallback: scratch in the zero-output planes, wiped by a final memset.
        f4* partial = (f4*)(out + 2 * N);
        f4* coef    = (f4*)(out + 3 * N);
        k_moments<<<BB * NG, 256, 0, stream>>>((const f4*)x, partial, scale);
        k_coef<<<BB, 64, 0, stream>>>(partial, coef,
                                      (float)(1.0 / S0), (float)(1.0 / S2),
                                      (float)(1.0 / Dd), (float)c20d);
        k_emit_fused<<<BB * 64, 256, 0, stream>>>((const f4*)x, coef, (f4*)out,
                                                  scale, (float)c20d);
        hipMemsetAsync(out + 2 * N, 0, 2 * N * sizeof(float), stream);
    }
}

// Round 3
// 63.738 us; speedup vs baseline: 1.0826x; 1.0826x over previous
//
#include <hip/hip_runtime.h>

typedef float f4 __attribute__((ext_vector_type(4)));

#define TT 4096
#define CC 128
#define BB 32
#define NG 64             // t-groups (64 rows each)
#define C4 (CC / 4)       // 32 float4 per row
#define ROWS_G (TT / NG)  // 64

// ---------------------------------------------------------------------------
// Kernel 1: partial moments m0 = sum x, m1 = sum u*x, m2 = sum u^2*x per
// (b, 64-row t-group, c). 2048 blocks x 256 thr (8 row-subgroups x 32 c-quads).
// partial layout: [b*64+g][3][C4] float4.
// ---------------------------------------------------------------------------
__global__ __launch_bounds__(256) void k_moments(const f4* __restrict__ x4,
                                                 f4* __restrict__ partial,
                                                 float scale) {
    const int blk = blockIdx.x;
    const int b = blk >> 6;
    const int g = blk & 63;
    const int tid = threadIdx.x;
    const int r = tid >> 5;    // 0..7
    const int q = tid & 31;    // 0..31
    const f4* xb = x4 + (size_t)b * TT * C4;
    const int t0 = g * ROWS_G;

    f4 m0 = (f4)0.0f, m1 = (f4)0.0f, m2 = (f4)0.0f;
#pragma unroll
    for (int k = 0; k < 8; ++k) {
        const int t = t0 + r + (k << 3);
        const float u = fmaf((float)t, scale, -0.5f);
        const f4 v = xb[(size_t)t * C4 + q];
        m0 += v;
        m1 += u * v;
        m2 += (u * u) * v;
    }

    __shared__ f4 red[3][8][32];
    red[0][r][q] = m0;
    red[1][r][q] = m1;
    red[2][r][q] = m2;
    __syncthreads();

    if (tid < 32) {
#pragma unroll
        for (int j = 0; j < 3; ++j) {
            f4 s = red[j][0][tid];
#pragma unroll
            for (int rr = 1; rr < 8; ++rr) s += red[j][rr][tid];
            partial[(size_t)blk * (3 * C4) + j * C4 + tid] = s;
        }
    }
}

// ---------------------------------------------------------------------------
// Kernel 2: each block reduces its batch's 64 partial records (L2-resident)
// to coefficients in LDS, then emits low/res (+ optionally the zero planes)
// for its 64-row tile with nontemporal streaming stores.
// ---------------------------------------------------------------------------
template <bool FUSE_ZERO>
__global__ __launch_bounds__(256) void k_emit(const f4* __restrict__ x4,
                                              const f4* __restrict__ partial,
                                              f4* __restrict__ out,
                                              float scale, float c20,
                                              float invS0, float invS2,
                                              float invD) {
    const size_t N4 = (size_t)BB * TT * C4;   // one output plane, f4 units
    const int blk = blockIdx.x;
    const int b = blk >> 6;
    const int g = blk & 63;
    const int tid = threadIdx.x;
    const int r = tid >> 5;
    const int q = tid & 31;

    __shared__ f4 red[3][8][32];
    __shared__ f4 ca[3][32];

    // Phase A: reduce the 64 partial records of batch b.
    const f4* pb = partial + (size_t)b * (64 * 3 * C4);
#pragma unroll
    for (int j = 0; j < 3; ++j) {
        f4 acc = (f4)0.0f;
#pragma unroll
        for (int k = 0; k < 8; ++k)
            acc += pb[(size_t)(r + (k << 3)) * (3 * C4) + j * C4 + q];
        red[j][r][q] = acc;
    }
    __syncthreads();
    if (tid < 32) {
        f4 s0 = (f4)0.0f, s1 = (f4)0.0f, s2 = (f4)0.0f;
#pragma unroll
        for (int rr = 0; rr < 8; ++rr) {
            s0 += red[0][rr][tid];
            s1 += red[1][rr][tid];
            s2 += red[2][rr][tid];
        }
        ca[0][tid] = s0 * invS0;
        ca[1][tid] = s1 * invS2;
        ca[2][tid] = (s2 - c20 * s0) * invD;
    }
    __syncthreads();

    const f4 a0 = ca[0][q];
    const f4 a1 = ca[1][q];
    const f4 a2 = ca[2][q];
    const f4 z = (f4)0.0f;

    // Phase B: emit 64 rows.
    const size_t base = (size_t)b * TT * C4;
    const int t0 = g * ROWS_G;
#pragma unroll
    for (int k = 0; k < 8; ++k) {
        const int t = t0 + r + (k << 3);
        const float u = fmaf((float)t, scale, -0.5f);
        const float w = fmaf(u, u, -c20);
        const size_t idx = base + (size_t)t * C4 + q;
        const f4 xv = x4[idx];
        const f4 lo = a0 + u * a1 + w * a2;
        const f4 re = xv - lo;
        __builtin_nontemporal_store(lo, &out[idx]);
        __builtin_nontemporal_store(re, &out[N4 + idx]);
        if (FUSE_ZERO) {
            __builtin_nontemporal_store(z, &out[2 * N4 + idx]);
            __builtin_nontemporal_store(z, &out[3 * N4 + idx]);
        }
    }
}

// ---------------------------------------------------------------------------
extern "C" void kernel_launch(void* const* d_in, const int* in_sizes, int n_in,
                              void* d_out, int out_size, void* d_ws, size_t ws_size,
                              hipStream_t stream) {
    const float* x = (const float*)d_in[0];
    float* out = (float*)d_out;
    const size_t N = (size_t)BB * TT * CC;   // elems per plane

    // Exact basis scalars in double on host (t symmetric => S1 = S3 = 0).
    double S0 = (double)TT, S2 = 0.0, S4 = 0.0;
    for (int i = 0; i < TT; ++i) {
        double u = (double)i / (double)(TT - 1) - 0.5;
        double u2 = u * u;
        S2 += u2;
        S4 += u2 * u2;
    }
    const double c20d = S2 / S0;
    const double Dd = S4 - S2 * S2 / S0;
    const float scale = (float)(1.0 / (double)(TT - 1));
    const float invS0 = (float)(1.0 / S0);
    const float invS2 = (float)(1.0 / S2);
    const float invD  = (float)(1.0 / Dd);
    const float c20   = (float)c20d;

    const size_t partial_elems = (size_t)BB * NG * 3 * C4;   // f4 units
    const size_t need_bytes    = partial_elems * sizeof(f4); // 3 MB

    if (ws_size >= need_bytes) {
        f4* partial = (f4*)d_ws;
        k_moments<<<BB * NG, 256, 0, stream>>>((const f4*)x, partial, scale);
        k_emit<true><<<BB * NG, 256, 0, stream>>>((const f4*)x, partial,
                                                  (f4*)out, scale, c20,
                                                  invS0, invS2, invD);
    } else {
        // Fallback: partials live in zero-plane 2; emit skips zero writes;
        // final memset wipes scratch and produces the zero planes.
        f4* partial = (f4*)(out + 2 * N);
        k_moments<<<BB * NG, 256, 0, stream>>>((const f4*)x, partial, scale);
        k_emit<false><<<BB * NG, 256, 0, stream>>>((const f4*)x, partial,
                                                   (f4*)out, scale, c20,
                                                   invS0, invS2, invD);
        hipMemsetAsync(out + 2 * N, 0, 2 * N * sizeof(float), stream);
    }
}

// Round 4
// 61.681 us; speedup vs baseline: 1.1187x; 1.0333x over previous
//
#include <hip/hip_runtime.h>

typedef float f4 __attribute__((ext_vector_type(4)));

#define TT 4096
#define CC 128
#define BB 32
#define C4 (CC / 4)        // 32 float4 per row
#define NGM 16             // moment slabs per batch (256 rows each)
#define SLAB (TT / NGM)    // 256
#define NTILE 64           // emit tiles per batch (64 rows each)

// ---------------------------------------------------------------------------
// Kernel 1 (split grid):
//   blocks [0, 512):     partial moments over a 256-row slab per (b, slab).
//   blocks [512, 2560):  nontemporal zero-fill of output planes 2 and 3.
// partial layout: [b*NGM+s][3][C4] float4  (512 records x 1.5 KB = 768 KB)
// ---------------------------------------------------------------------------
__global__ __launch_bounds__(256) void k_moments_zero(const f4* __restrict__ x4,
                                                      f4* __restrict__ partial,
                                                      f4* __restrict__ out,
                                                      float scale) {
    const size_t N4 = (size_t)BB * TT * C4;   // one output plane, f4 units
    const int blk = blockIdx.x;
    const int tid = threadIdx.x;
    const int r = tid >> 5;    // 0..7
    const int q = tid & 31;    // 0..31

    if (blk < BB * NGM) {
        // ----- moment blocks -----
        const int b = blk >> 4;
        const int s = blk & 15;
        const f4* xb = x4 + (size_t)b * TT * C4;
        const int t0 = s * SLAB;

        f4 m0 = (f4)0.0f, m1 = (f4)0.0f, m2 = (f4)0.0f;
#pragma unroll 8
        for (int k = 0; k < SLAB / 8; ++k) {   // 32 iterations
            const int t = t0 + r + (k << 3);
            const float u = fmaf((float)t, scale, -0.5f);
            const f4 v = xb[(size_t)t * C4 + q];
            m0 += v;
            m1 += u * v;
            m2 += (u * u) * v;
        }

        __shared__ f4 red[3][8][32];
        red[0][r][q] = m0;
        red[1][r][q] = m1;
        red[2][r][q] = m2;
        __syncthreads();

        if (tid < 32) {
#pragma unroll
            for (int j = 0; j < 3; ++j) {
                f4 acc = red[j][0][tid];
#pragma unroll
                for (int rr = 1; rr < 8; ++rr) acc += red[j][rr][tid];
                partial[(size_t)blk * (3 * C4) + j * C4 + tid] = acc;
            }
        }
    } else {
        // ----- zero-fill blocks: planes 2 and 3, one 64-row tile each -----
        const int zid = blk - BB * NGM;        // 0..2047
        const int b = zid >> 6;
        const int tile = zid & 63;
        const size_t base = (size_t)b * TT * C4 + (size_t)(tile * 64) * C4;
        const f4 z = (f4)0.0f;
#pragma unroll
        for (int k = 0; k < 8; ++k) {
            const size_t idx = base + (size_t)(r + (k << 3)) * C4 + q;
            __builtin_nontemporal_store(z, &out[2 * N4 + idx]);
            __builtin_nontemporal_store(z, &out[3 * N4 + idx]);
        }
    }
}

// ---------------------------------------------------------------------------
// Kernel 2: reduce the batch's 16 partial records to coefficients (cheap),
// then emit low/res for a 64-row tile with nontemporal streaming stores.
// ---------------------------------------------------------------------------
template <bool FUSE_ZERO>
__global__ __launch_bounds__(256) void k_emit(const f4* __restrict__ x4,
                                              const f4* __restrict__ partial,
                                              f4* __restrict__ out,
                                              float scale, float c20,
                                              float invS0, float invS2,
                                              float invD) {
    const size_t N4 = (size_t)BB * TT * C4;
    const int blk = blockIdx.x;
    const int b = blk >> 6;
    const int tile = blk & 63;
    const int tid = threadIdx.x;
    const int r = tid >> 5;
    const int q = tid & 31;

    __shared__ f4 red[3][8][32];
    __shared__ f4 ca[3][32];

    // Phase A: reduce 16 partial records of batch b (thread reads 6 f4).
    const f4* pb = partial + (size_t)b * (NGM * 3 * C4);
#pragma unroll
    for (int j = 0; j < 3; ++j) {
        const f4 e0 = pb[(size_t)(2 * r + 0) * (3 * C4) + j * C4 + q];
        const f4 e1 = pb[(size_t)(2 * r + 1) * (3 * C4) + j * C4 + q];
        red[j][r][q] = e0 + e1;
    }
    __syncthreads();
    if (tid < 32) {
        f4 s0 = (f4)0.0f, s1 = (f4)0.0f, s2 = (f4)0.0f;
#pragma unroll
        for (int rr = 0; rr < 8; ++rr) {
            s0 += red[0][rr][tid];
            s1 += red[1][rr][tid];
            s2 += red[2][rr][tid];
        }
        ca[0][tid] = s0 * invS0;
        ca[1][tid] = s1 * invS2;
        ca[2][tid] = (s2 - c20 * s0) * invD;
    }
    __syncthreads();

    const f4 a0 = ca[0][q];
    const f4 a1 = ca[1][q];
    const f4 a2 = ca[2][q];
    const f4 z = (f4)0.0f;

    // Phase B: emit 64 rows (low, res; zeros only in fallback-free mode).
    const size_t base = (size_t)b * TT * C4;
    const int t0 = tile * 64;
#pragma unroll
    for (int k = 0; k < 8; ++k) {
        const int t = t0 + r + (k << 3);
        const float u = fmaf((float)t, scale, -0.5f);
        const float w = fmaf(u, u, -c20);
        const size_t idx = base + (size_t)t * C4 + q;
        const f4 xv = x4[idx];
        const f4 lo = a0 + u * a1 + w * a2;
        const f4 re = xv - lo;
        __builtin_nontemporal_store(lo, &out[idx]);
        __builtin_nontemporal_store(re, &out[N4 + idx]);
        if (FUSE_ZERO) {
            __builtin_nontemporal_store(z, &out[2 * N4 + idx]);
            __builtin_nontemporal_store(z, &out[3 * N4 + idx]);
        }
    }
}

// Moments-only kernel for the fallback path (no zero-fill blocks).
__global__ __launch_bounds__(256) void k_moments_only(const f4* __restrict__ x4,
                                                      f4* __restrict__ partial,
                                                      float scale) {
    const int blk = blockIdx.x;
    const int tid = threadIdx.x;
    const int r = tid >> 5;
    const int q = tid & 31;
    const int b = blk >> 4;
    const int s = blk & 15;
    const f4* xb = x4 + (size_t)b * TT * C4;
    const int t0 = s * SLAB;

    f4 m0 = (f4)0.0f, m1 = (f4)0.0f, m2 = (f4)0.0f;
#pragma unroll 8
    for (int k = 0; k < SLAB / 8; ++k) {
        const int t = t0 + r + (k << 3);
        const float u = fmaf((float)t, scale, -0.5f);
        const f4 v = xb[(size_t)t * C4 + q];
        m0 += v;
        m1 += u * v;
        m2 += (u * u) * v;
    }

    __shared__ f4 red[3][8][32];
    red[0][r][q] = m0;
    red[1][r][q] = m1;
    red[2][r][q] = m2;
    __syncthreads();

    if (tid < 32) {
#pragma unroll
        for (int j = 0; j < 3; ++j) {
            f4 acc = red[j][0][tid];
#pragma unroll
            for (int rr = 1; rr < 8; ++rr) acc += red[j][rr][tid];
            partial[(size_t)blk * (3 * C4) + j * C4 + tid] = acc;
        }
    }
}

// ---------------------------------------------------------------------------
extern "C" void kernel_launch(void* const* d_in, const int* in_sizes, int n_in,
                              void* d_out, int out_size, void* d_ws, size_t ws_size,
                              hipStream_t stream) {
    const float* x = (const float*)d_in[0];
    float* out = (float*)d_out;
    const size_t N = (size_t)BB * TT * CC;   // elems per plane

    // Exact basis scalars in double on host (t symmetric => S1 = S3 = 0).
    double S0 = (double)TT, S2 = 0.0, S4 = 0.0;
    for (int i = 0; i < TT; ++i) {
        double u = (double)i / (double)(TT - 1) - 0.5;
        double u2 = u * u;
        S2 += u2;
        S4 += u2 * u2;
    }
    const double c20d = S2 / S0;
    const double Dd = S4 - S2 * S2 / S0;
    const float scale = (float)(1.0 / (double)(TT - 1));
    const float invS0 = (float)(1.0 / S0);
    const float invS2 = (float)(1.0 / S2);
    const float invD  = (float)(1.0 / Dd);
    const float c20   = (float)c20d;

    const size_t partial_elems = (size_t)BB * NGM * 3 * C4;   // f4 units
    const size_t need_bytes    = partial_elems * sizeof(f4);  // 768 KB

    if (ws_size >= need_bytes) {
        f4* partial = (f4*)d_ws;
        k_moments_zero<<<BB * NGM + BB * NTILE, 256, 0, stream>>>(
            (const f4*)x, partial, (f4*)out, scale);
        k_emit<false><<<BB * NTILE, 256, 0, stream>>>(
            (const f4*)x, partial, (f4*)out, scale, c20, invS0, invS2, invD);
    } else {
        // Fallback: partials live in zero-plane 2; final memset wipes them
        // and produces the zero planes.
        f4* partial = (f4*)(out + 2 * N);
        k_moments_only<<<BB * NGM, 256, 0, stream>>>((const f4*)x, partial,
                                                     scale);
        k_emit<false><<<BB * NTILE, 256, 0, stream>>>(
            (const f4*)x, partial, (f4*)out, scale, c20, invS0, invS2, invD);
        hipMemsetAsync(out + 2 * N, 0, 2 * N * sizeof(float), stream);
    }
}

// Round 6
// 61.573 us; speedup vs baseline: 1.1207x; 1.0018x over previous
//
#include <hip/hip_runtime.h>
#include <hip/hip_cooperative_groups.h>

namespace cg = cooperative_groups;

typedef float f4 __attribute__((ext_vector_type(4)));

#define TT 4096
#define CC 128
#define BB 32
#define C4 (CC / 4)        // 32 float4 per row
#define NB 1024            // cooperative grid: 32 blocks per batch
#define ROWS_B 128         // rows per block (TT / 32)
#define RECS 32            // partial records per batch

// ---------------------------------------------------------------------------
// Fused cooperative kernel: moments -> grid.sync -> reduce -> emit.
// 1024 blocks x 256 thr; needs 4 blocks/CU co-resident.
// partial layout: [NB][3][C4] float4 (1.5 MB in d_ws).
// ---------------------------------------------------------------------------
__global__ __launch_bounds__(256, 4) void k_fused(const f4* __restrict__ x4,
                                                  f4* __restrict__ partial,
                                                  f4* __restrict__ out,
                                                  float scale, float c20,
                                                  float invS0, float invS2,
                                                  float invD) {
    const size_t N4 = (size_t)BB * TT * C4;   // one output plane, f4 units
    const int blk = blockIdx.x;
    const int b = blk >> 5;      // 32 blocks per batch
    const int tile = blk & 31;   // which 128-row tile
    const int tid = threadIdx.x;
    const int r = tid >> 5;      // 0..7
    const int q = tid & 31;      // 0..31

    __shared__ f4 red[3][8][32];
    __shared__ f4 ca[3][32];

    const size_t base = (size_t)b * TT * C4;
    const int t0 = tile * ROWS_B;

    // ---- Phase 1: partial moments over this block's 128 rows ----
    f4 m0 = (f4)0.0f, m1 = (f4)0.0f, m2 = (f4)0.0f;
#pragma unroll
    for (int k = 0; k < ROWS_B / 8; ++k) {   // 16 iterations
        const int t = t0 + r + (k << 3);
        const float u = fmaf((float)t, scale, -0.5f);
        const f4 v = x4[base + (size_t)t * C4 + q];
        m0 += v;
        m1 += u * v;
        m2 += (u * u) * v;
    }
    red[0][r][q] = m0;
    red[1][r][q] = m1;
    red[2][r][q] = m2;
    __syncthreads();
    if (tid < 32) {
#pragma unroll
        for (int j = 0; j < 3; ++j) {
            f4 acc = red[j][0][tid];
#pragma unroll
            for (int rr = 1; rr < 8; ++rr) acc += red[j][rr][tid];
            partial[(size_t)blk * (3 * C4) + j * C4 + tid] = acc;
        }
    }

    // ---- grid-wide barrier (device-scope fence: partials visible) ----
    cg::this_grid().sync();

    // ---- Phase 2: reduce this batch's 32 records (L2/L3-resident) ----
    const f4* pb = partial + (size_t)b * (RECS * 3 * C4);
#pragma unroll
    for (int j = 0; j < 3; ++j) {
        f4 acc = (f4)0.0f;
#pragma unroll
        for (int k = 0; k < 4; ++k)
            acc += pb[(size_t)(4 * r + k) * (3 * C4) + j * C4 + q];
        red[j][r][q] = acc;
    }
    __syncthreads();
    if (tid < 32) {
        f4 s0 = (f4)0.0f, s1 = (f4)0.0f, s2 = (f4)0.0f;
#pragma unroll
        for (int rr = 0; rr < 8; ++rr) {
            s0 += red[0][rr][tid];
            s1 += red[1][rr][tid];
            s2 += red[2][rr][tid];
        }
        ca[0][tid] = s0 * invS0;
        ca[1][tid] = s1 * invS2;
        ca[2][tid] = (s2 - c20 * s0) * invD;
    }
    __syncthreads();

    const f4 a0 = ca[0][q];
    const f4 a1 = ca[1][q];
    const f4 a2 = ca[2][q];
    const f4 z = (f4)0.0f;

    // ---- Phase 3: emit all four planes for this block's rows ----
#pragma unroll
    for (int k = 0; k < ROWS_B / 8; ++k) {
        const int t = t0 + r + (k << 3);
        const float u = fmaf((float)t, scale, -0.5f);
        const float w = fmaf(u, u, -c20);
        const size_t idx = base + (size_t)t * C4 + q;
        const f4 xv = x4[idx];   // L3-hot: same rows read in phase 1
        const f4 lo = a0 + u * a1 + w * a2;
        const f4 re = xv - lo;
        __builtin_nontemporal_store(lo, &out[idx]);
        __builtin_nontemporal_store(re, &out[N4 + idx]);
        __builtin_nontemporal_store(z, &out[2 * N4 + idx]);
        __builtin_nontemporal_store(z, &out[3 * N4 + idx]);
    }
}

// ===========================================================================
// Fallback path (R4 structure, measured 61.7 us): two kernels.
// ===========================================================================
#define NGM 16
#define SLAB (TT / NGM)
#define NTILE 64

__global__ __launch_bounds__(256) void k_moments_zero(const f4* __restrict__ x4,
                                                      f4* __restrict__ partial,
                                                      f4* __restrict__ out,
                                                      float scale) {
    const size_t N4 = (size_t)BB * TT * C4;
    const int blk = blockIdx.x;
    const int tid = threadIdx.x;
    const int r = tid >> 5;
    const int q = tid & 31;

    if (blk < BB * NGM) {
        const int b = blk >> 4;
        const int s = blk & 15;
        const f4* xb = x4 + (size_t)b * TT * C4;
        const int t0 = s * SLAB;
        f4 m0 = (f4)0.0f, m1 = (f4)0.0f, m2 = (f4)0.0f;
#pragma unroll 8
        for (int k = 0; k < SLAB / 8; ++k) {
            const int t = t0 + r + (k << 3);
            const float u = fmaf((float)t, scale, -0.5f);
            const f4 v = xb[(size_t)t * C4 + q];
            m0 += v;
            m1 += u * v;
            m2 += (u * u) * v;
        }
        __shared__ f4 red[3][8][32];
        red[0][r][q] = m0;
        red[1][r][q] = m1;
        red[2][r][q] = m2;
        __syncthreads();
        if (tid < 32) {
#pragma unroll
            for (int j = 0; j < 3; ++j) {
                f4 acc = red[j][0][tid];
#pragma unroll
                for (int rr = 1; rr < 8; ++rr) acc += red[j][rr][tid];
                partial[(size_t)blk * (3 * C4) + j * C4 + tid] = acc;
            }
        }
    } else {
        const int zid = blk - BB * NGM;
        const int b = zid >> 6;
        const int tile = zid & 63;
        const size_t base = (size_t)b * TT * C4 + (size_t)(tile * 64) * C4;
        const f4 z = (f4)0.0f;
#pragma unroll
        for (int k = 0; k < 8; ++k) {
            const size_t idx = base + (size_t)(r + (k << 3)) * C4 + q;
            __builtin_nontemporal_store(z, &out[2 * N4 + idx]);
            __builtin_nontemporal_store(z, &out[3 * N4 + idx]);
        }
    }
}

__global__ __launch_bounds__(256) void k_emit(const f4* __restrict__ x4,
                                              const f4* __restrict__ partial,
                                              f4* __restrict__ out,
                                              float scale, float c20,
                                              float invS0, float invS2,
                                              float invD) {
    const size_t N4 = (size_t)BB * TT * C4;
    const int blk = blockIdx.x;
    const int b = blk >> 6;
    const int tile = blk & 63;
    const int tid = threadIdx.x;
    const int r = tid >> 5;
    const int q = tid & 31;

    __shared__ f4 red[3][8][32];
    __shared__ f4 ca[3][32];

    const f4* pb = partial + (size_t)b * (NGM * 3 * C4);
#pragma unroll
    for (int j = 0; j < 3; ++j) {
        const f4 e0 = pb[(size_t)(2 * r + 0) * (3 * C4) + j * C4 + q];
        const f4 e1 = pb[(size_t)(2 * r + 1) * (3 * C4) + j * C4 + q];
        red[j][r][q] = e0 + e1;
    }
    __syncthreads();
    if (tid < 32) {
        f4 s0 = (f4)0.0f, s1 = (f4)0.0f, s2 = (f4)0.0f;
#pragma unroll
        for (int rr = 0; rr < 8; ++rr) {
            s0 += red[0][rr][tid];
            s1 += red[1][rr][tid];
            s2 += red[2][rr][tid];
        }
        ca[0][tid] = s0 * invS0;
        ca[1][tid] = s1 * invS2;
        ca[2][tid] = (s2 - c20 * s0) * invD;
    }
    __syncthreads();

    const f4 a0 = ca[0][q];
    const f4 a1 = ca[1][q];
    const f4 a2 = ca[2][q];

    const size_t base = (size_t)b * TT * C4;
    const int t0 = tile * 64;
#pragma unroll
    for (int k = 0; k < 8; ++k) {
        const int t = t0 + r + (k << 3);
        const float u = fmaf((float)t, scale, -0.5f);
        const float w = fmaf(u, u, -c20);
        const size_t idx = base + (size_t)t * C4 + q;
        const f4 xv = x4[idx];
        const f4 lo = a0 + u * a1 + w * a2;
        const f4 re = xv - lo;
        __builtin_nontemporal_store(lo, &out[idx]);
        __builtin_nontemporal_store(re, &out[N4 + idx]);
    }
}

// ---------------------------------------------------------------------------
extern "C" void kernel_launch(void* const* d_in, const int* in_sizes, int n_in,
                              void* d_out, int out_size, void* d_ws, size_t ws_size,
                              hipStream_t stream) {
    const float* x = (const float*)d_in[0];
    float* out = (float*)d_out;
    const size_t N = (size_t)BB * TT * CC;

    // Exact basis scalars in double on host (t symmetric => S1 = S3 = 0).
    double S0 = (double)TT, S2 = 0.0, S4 = 0.0;
    for (int i = 0; i < TT; ++i) {
        double u = (double)i / (double)(TT - 1) - 0.5;
        double u2 = u * u;
        S2 += u2;
        S4 += u2 * u2;
    }
    const double c20d = S2 / S0;
    const double Dd = S4 - S2 * S2 / S0;
    float scale = (float)(1.0 / (double)(TT - 1));
    float invS0 = (float)(1.0 / S0);
    float invS2 = (float)(1.0 / S2);
    float invD  = (float)(1.0 / Dd);
    float c20   = (float)c20d;

    const size_t coop_need = (size_t)NB * 3 * C4 * sizeof(f4);   // 1.5 MB

    // --- Attempt cooperative fused path, with full validation + fallback ---
    if (ws_size >= coop_need) {
        int dev = 0, coop = 0, cus = 0, occ = 0;
        if (hipGetDevice(&dev) == hipSuccess &&
            hipDeviceGetAttribute(&coop, hipDeviceAttributeCooperativeLaunch,
                                  dev) == hipSuccess &&
            coop &&
            hipDeviceGetAttribute(&cus, hipDeviceAttributeMultiprocessorCount,
                                  dev) == hipSuccess &&
            hipOccupancyMaxActiveBlocksPerMultiprocessor(
                &occ, (const void*)k_fused, 256, 0) == hipSuccess &&
            occ * cus >= NB) {
            const f4* x4 = (const f4*)x;
            f4* partial = (f4*)d_ws;
            f4* out4 = (f4*)out;
            void* args[] = {(void*)&x4, (void*)&partial, (void*)&out4,
                            (void*)&scale, (void*)&c20,
                            (void*)&invS0, (void*)&invS2, (void*)&invD};
            hipError_t err = hipLaunchCooperativeKernel(
                (const void*)k_fused, dim3(NB), dim3(256), args, 0, stream);
            if (err == hipSuccess) return;   // fused path launched
            // else: fall through to the proven two-kernel path
        }
    }

    // --- Fallback: proven two-kernel path (R4, 61.7 us) ---
    const size_t fb_need = (size_t)BB * NGM * 3 * C4 * sizeof(f4);
    if (ws_size >= fb_need) {
        f4* partial = (f4*)d_ws;
        k_moments_zero<<<BB * NGM + BB * NTILE, 256, 0, stream>>>(
            (const f4*)x, partial, (f4*)out, scale);
        k_emit<<<BB * NTILE, 256, 0, stream>>>(
            (const f4*)x, partial, (f4*)out, scale, c20, invS0, invS2, invD);
    } else {
        f4* partial = (f4*)(out + 2 * N);
        k_moments_zero<<<BB * NGM, 256, 0, stream>>>(
            (const f4*)x, partial, (f4*)out, scale);
        k_emit<<<BB * NTILE, 256, 0, stream>>>(
            (const f4*)x, partial, (f4*)out, scale, c20, invS0, invS2, invD);
        hipMemsetAsync(out + 2 * N, 0, 2 * N * sizeof(float), stream);
    }
}